// Round 1
// baseline (246.276 us; speedup 1.0000x reference)
//
#include <hip/hip_runtime.h>

// GraphConv: out = relu( D * A_hat * D * x * W ),  B=8, N=2048, F=O=128, fp32.
// Reassociated: out[n,o] = relu( d[n] * sum_m A_hat[n,m] * y[m,o] ),
//   y[m,o] = d[m] * (x @ W)[m,o]  (stored transposed, bf16)
// K0: Wt = W^T bf16          (tiny)
// K1: d[b,n] = 1/(eps+sqrt(rowsum(A_hat)))   (one pass over adj, HBM-bound)
// K2: y_t[b][o][m] = bf16(d*xW)   (MFMA GEMM, K=128)
// K3: out = relu(d[n] * A_hat_bf16 @ y)      (MFMA GEMM, K=2048, in-kernel
//     fp32->bf16 convert of adj with diag->1 fix; y staged via global_load_lds)

typedef __bf16 bf16x8 __attribute__((ext_vector_type(8)));
typedef float  f32x4  __attribute__((ext_vector_type(4)));

#define NN 2048
#define NB 8

__device__ __forceinline__ void load_lds16(__bf16* lds, const __bf16* g) {
    // per-lane global src, wave-uniform LDS base; dest = base + lane*16
    __builtin_amdgcn_global_load_lds(
        (const __attribute__((address_space(1))) void*)g,
        (__attribute__((address_space(3))) void*)lds, 16, 0, 0);
}

// ---------------- K0: W [128][128] fp32 -> Wt [o][f] bf16 ----------------
__global__ __launch_bounds__(256) void wt_kernel(const float* __restrict__ W,
                                                 __bf16* __restrict__ Wt) {
    int idx = blockIdx.x * 256 + threadIdx.x;   // grid 64 -> 16384
    int f = idx >> 7, o = idx & 127;
    Wt[o * 128 + f] = (__bf16)W[idx];
}

// ---------------- K1: degree vector ----------------
__global__ __launch_bounds__(256) void d_kernel(const float* __restrict__ adj,
                                                float* __restrict__ dvec) {
    const int lane = threadIdx.x & 63;
    const int row  = blockIdx.x * 4 + (threadIdx.x >> 6);   // one wave per row
    const float* rp = adj + (size_t)row * NN;
    float4 s4 = {0.f, 0.f, 0.f, 0.f};
#pragma unroll
    for (int it = 0; it < 8; ++it) {
        float4 v = *(const float4*)(rp + it * 256 + lane * 4);
        s4.x += v.x; s4.y += v.y; s4.z += v.z; s4.w += v.w;
    }
    float s = (s4.x + s4.y) + (s4.z + s4.w);
#pragma unroll
    for (int off = 32; off; off >>= 1) s += __shfl_down(s, off);
    if (lane == 0) {
        int n = row & (NN - 1);
        float sh = s - rp[n] + 1.0f;            // zero diag, add self-loop
        dvec[row] = 1.0f / (1e-6f + sqrtf(sh));
    }
}

// ---------------- K2/K3: MFMA GEMM ----------------
// Block: 256 thr (4 waves). Tile: 64 rows x 128 cols, BK=32, 16x16x32 bf16.
// A: [B*2048][KTOT] fp32 (x or adj), staged via regs->cvt->LDS.
// Bmat: bf16, row = output col o, K-contiguous (Wt or y_t per batch).
template <int KTOT, bool IS_XW>
__global__ __launch_bounds__(256) void gemm_kernel(
    const float* __restrict__ A, const __bf16* __restrict__ Bmat,
    const float* __restrict__ dvec, float* __restrict__ out,
    __bf16* __restrict__ yt) {
    __shared__ alignas(16) __bf16 sA[64][40];   // +8 pad: conflict-free frag reads
    __shared__ alignas(16) __bf16 sB[128][32];  // unpadded (global_load_lds layout)

    const int tid  = threadIdx.x;
    const int wave = tid >> 6;
    const int lane = tid & 63;
    const int b    = blockIdx.y;
    const int n_local_base = blockIdx.x * 64;
    const int row_base = b * NN + n_local_base;   // flat row in [B*2048]

    const __bf16* Bptr = IS_XW ? Bmat : (Bmat + (size_t)b * 128 * KTOT);

    // A staging map: thread -> (row 0..63, 8 contiguous cols)
    const int a_row = tid >> 2;
    const int a_col = (tid & 3) * 8;
    const float* a_src = A + (size_t)(row_base + a_row) * KTOT + a_col;

    f32x4 acc[8];
#pragma unroll
    for (int i = 0; i < 8; ++i) acc[i] = (f32x4){0.f, 0.f, 0.f, 0.f};

    // prefetch A regs for iter 0
    f32x4 a0 = *(const f32x4*)(a_src);
    f32x4 a1 = *(const f32x4*)(a_src + 4);

    const int NITER = KTOT / 32;
    for (int kt = 0; kt < NITER; ++kt) {
        // ---- stage A: convert (+diag fix) -> LDS ----
        float av[8] = {a0.x, a0.y, a0.z, a0.w, a1.x, a1.y, a1.z, a1.w};
        if constexpr (!IS_XW) {
            int n  = n_local_base + a_row;
            int m0 = kt * 32 + a_col;
#pragma unroll
            for (int j = 0; j < 8; ++j)
                if (m0 + j == n) av[j] = 1.0f;   // A_hat diagonal = 1
        }
        bf16x8 apack;
#pragma unroll
        for (int j = 0; j < 8; ++j) apack[j] = (__bf16)av[j];
        *(bf16x8*)(&sA[a_row][a_col]) = apack;

        // ---- stage B: async global->LDS, 16 rows x 64B per call ----
        {
            int row0 = wave * 32;
            const __bf16* src0 =
                Bptr + (size_t)(row0 + (lane >> 2)) * KTOT + kt * 32 + (lane & 3) * 8;
            load_lds16(&sB[row0][0], src0);
            load_lds16(&sB[row0 + 16][0], src0 + (size_t)16 * KTOT);
        }
        __syncthreads();

        // prefetch next A tile into regs (hides HBM latency behind MFMA)
        if (kt + 1 < NITER) {
            a0 = *(const f32x4*)(a_src + (size_t)(kt + 1) * 32);
            a1 = *(const f32x4*)(a_src + (size_t)(kt + 1) * 32 + 4);
        }

        // ---- MFMA: wave w owns rows [w*16, w*16+16) x all 128 cols ----
        bf16x8 af = *(const bf16x8*)(&sA[wave * 16 + (lane & 15)][(lane >> 4) * 8]);
#pragma unroll
        for (int nb = 0; nb < 8; ++nb) {
            bf16x8 bf = *(const bf16x8*)(&sB[nb * 16 + (lane & 15)][(lane >> 4) * 8]);
            acc[nb] = __builtin_amdgcn_mfma_f32_16x16x32_bf16(af, bf, acc[nb], 0, 0, 0);
        }
        __syncthreads();
    }

    // ---- epilogue: C/D layout col=lane&15, row=(lane>>4)*4+reg ----
    const int col0 = lane & 15;
    const int rq   = (lane >> 4) * 4;
#pragma unroll
    for (int r = 0; r < 4; ++r) {
        int grow = row_base + wave * 16 + rq + r;   // flat row
        float dr = dvec[grow];
        if constexpr (IS_XW) {
            int m_loc = grow - b * NN;
#pragma unroll
            for (int nb = 0; nb < 8; ++nb) {
                int o = nb * 16 + col0;
                yt[((size_t)b * 128 + o) * NN + m_loc] = (__bf16)(acc[nb][r] * dr);
            }
        } else {
#pragma unroll
            for (int nb = 0; nb < 8; ++nb) {
                int o = nb * 16 + col0;
                float v = acc[nb][r] * dr;
                out[(size_t)grow * 128 + o] = v > 0.f ? v : 0.f;
            }
        }
    }
}

extern "C" void kernel_launch(void* const* d_in, const int* in_sizes, int n_in,
                              void* d_out, int out_size, void* d_ws, size_t ws_size,
                              hipStream_t stream) {
    const float* x   = (const float*)d_in[0];   // [8,2048,128]
    const float* adj = (const float*)d_in[1];   // [8,2048,2048]
    const float* W   = (const float*)d_in[2];   // [128,128]
    float* out = (float*)d_out;

    char* ws = (char*)d_ws;
    float*  dvec = (float*)ws;                              // 64 KB
    __bf16* yt   = (__bf16*)(ws + 65536);                   // 4 MB  [B][128][2048]
    __bf16* Wt   = (__bf16*)(ws + 65536 + (size_t)NB * 128 * NN * 2);  // 32 KB

    hipLaunchKernelGGL(wt_kernel, dim3(64), dim3(256), 0, stream, W, Wt);
    hipLaunchKernelGGL(d_kernel, dim3(NB * NN / 4), dim3(256), 0, stream, adj, dvec);
    hipLaunchKernelGGL((gemm_kernel<128, true>), dim3(32, NB), dim3(256), 0, stream,
                       x, Wt, dvec, (float*)nullptr, yt);
    hipLaunchKernelGGL((gemm_kernel<2048, false>), dim3(32, NB), dim3(256), 0, stream,
                       adj, yt, dvec, out, (__bf16*)nullptr);
}